// Round 10
// baseline (65.071 us; speedup 1.0000x reference)
//
#include <hip/hip_runtime.h>
#include <hip/hip_cooperative_groups.h>

namespace cg = cooperative_groups;

// GraphSearchPolicy, single cooperative MFMA kernel. MI355X gfx950.
// B=2048, A=256, DE=128, DH=256, DR=128, DIN=512, ACT=256, NR=1000.
//
// Phase A (pre-sync): grid-distributed pack of W1/W2/rel_emb^T into bf16
// MFMA B-fragment tiles in d_ws (36608 lane-jobs) + per-block X staging.
// grid.sync() (grid = 256 blocks = 1/CU, co-resident by construction).
// Phase B: three GEMMs via mfma_f32_16x16x32_bf16 with hi/lo split packed
// into M-rows 0-7 (hi) / 8-15 (lo): one MFMA per (kt,ntile); the hi+lo sum
// is 4 shfl_xor(.,32) in the epilogue (C rows r / r+8 live in lanes l / l+32).
// C mapping (HW-verified): col = lane&15, row = (lane>>4)*4 + reg.

#define DE   128
#define DH   256
#define DR   128
#define DIN  512
#define ACT  256
#define AA   256
#define BB   8
#define NR   1000
#define SCL  1008            // padded score width (63 n-tiles)

#define XS_P 520             // xs row stride (floats)
#define HS_P 264             // hs row stride
#define X2_P 136             // x2 row stride

#define W2B_OFF 16384        // uint4 offsets into d_ws
#define RB_OFF  20480
#define PREP_T  36608        // 572 tiles * 64 lanes

typedef __attribute__((ext_vector_type(4))) float f32x4;
typedef __attribute__((ext_vector_type(8))) short s16x8;
typedef unsigned int u32;

#define MFMA(a,b,c) __builtin_amdgcn_mfma_f32_16x16x32_bf16(a, b, c, 0, 0, 0)

__device__ __forceinline__ u32 b16(float x) {            // fp32 -> bf16 (RNE)
    u32 u = __float_as_uint(x);
    return (u + 0x7FFFu + ((u >> 16) & 1u)) >> 16;
}
__device__ __forceinline__ float b16f(u32 h) { return __uint_as_float(h << 16); }
__device__ __forceinline__ u32 pack2(float a, float b) { return b16(a) | (b16(b) << 16); }

__device__ __forceinline__ s16x8 asfrag(uint4 v) {
    union { uint4 u; s16x8 s; } c; c.u = v; return c.s;
}

// 8 consecutive fp32 -> ONE bf16 fragment: hi part if !lo, residual if lo.
__device__ __forceinline__ uint4 build_one(const float* p, bool lo) {
    const float4 a = *(const float4*)p;
    const float4 b = *(const float4*)(p + 4);
    const float f[8] = {a.x, a.y, a.z, a.w, b.x, b.y, b.z, b.w};
    u32 o[8];
    #pragma unroll
    for (int i = 0; i < 8; ++i) {
        const u32  h = b16(f[i]);
        const float r = f[i] - b16f(h);
        o[i] = lo ? b16(r) : h;
    }
    uint4 v;
    v.x = o[0] | (o[1] << 16); v.y = o[2] | (o[3] << 16);
    v.z = o[4] | (o[5] << 16); v.w = o[6] | (o[7] << 16);
    return v;
}

// ---------------------------------------------------------------- kernel
__global__ __launch_bounds__(512, 2) void policy_kernel(
    const int*   __restrict__ e,
    const int*   __restrict__ q,
    const float* __restrict__ H,
    const int*   __restrict__ r_space,
    const float* __restrict__ r_mask,
    const float* __restrict__ entity_emb,
    const float* __restrict__ rel_emb,
    const float* __restrict__ W1,
    const float* __restrict__ b1,
    const float* __restrict__ W2,
    const float* __restrict__ b2,
    uint4*       __restrict__ wsb,
    float*       __restrict__ dist_out,
    float*       __restrict__ ent_out)
{
    const int t  = threadIdx.x;          // 0..511
    const int b0 = blockIdx.x * BB;
    const int l  = t & 63;
    const int w  = t >> 6;               // wave 0..7
    const int m  = l & 15;               // fragment row slot
    const int arow = m & 7;              // source batch row
    const bool lo  = (m >= 8);           // lanes 8-15: residual rows
    const int kb_l = (l >> 4) * 8;

    __shared__ __align__(16) float xs[BB * XS_P];    // 16.6 KB
    __shared__ __align__(16) float hs[BB * HS_P];    //  8.4 KB
    __shared__ __align__(16) float x2s[BB * X2_P];   //  4.3 KB
    __shared__ float scoreL[BB * SCL];               // 31.5 KB
    __shared__ float wredM[8][4], wredS[8][4], wredL[8][4];

    // ================= Phase A: B-fragment packing (grid-distributed) =======
    {
        const int gid = blockIdx.x * 512 + t;        // 0..131071
        if (gid < PREP_T) {
            const int pl = gid & 63;
            const int tl = gid >> 6;                 // tile 0..571
            const int pkb = (pl >> 4) * 8;
            const int pn  = pl & 15;
            float f[8];
            if (tl < 256) {                          // W1B: tl = kt*16+nt
                const int kt = tl >> 4, nt = tl & 15;
                const int kb = kt * 32 + pkb, n = nt * 16 + pn;
                #pragma unroll
                for (int i = 0; i < 8; ++i) f[i] = W1[(size_t)(kb + i) * ACT + n];
            } else if (tl < 320) {                   // W2B
                const int t2 = tl - 256;
                const int kt = t2 >> 3, nt = t2 & 7;
                const int kb = kt * 32 + pkb, n = nt * 16 + pn;
                #pragma unroll
                for (int i = 0; i < 8; ++i) f[i] = W2[(size_t)(kb + i) * DR + n];
            } else {                                 // RB: tl-320 = nt*4+kt
                const int t3 = tl - 320;             // 0..251
                const int nt = t3 >> 2, kt = t3 & 3;
                const int kb = kt * 32 + pkb, n = nt * 16 + pn;
                #pragma unroll
                for (int i = 0; i < 8; ++i)
                    f[i] = (n < NR) ? rel_emb[(size_t)n * DR + kb + i] : 0.f;
            }
            uint4 o;
            o.x = pack2(f[0], f[1]); o.y = pack2(f[2], f[3]);
            o.z = pack2(f[4], f[5]); o.w = pack2(f[6], f[7]);
            wsb[gid] = o;
        }
    }

    // ---- X staging (independent of wsb): float4, 2 jobs/thread ----
    #pragma unroll
    for (int u = 0; u < 2; ++u) {
        const int j   = t + u * 512;     // 0..1023
        const int row = j & 7;
        const int k   = (j >> 3) * 4;    // 0..508
        const int sb  = b0 + row;
        float4 v;
        if (k < DE)            v = *(const float4*)&entity_emb[(size_t)e[sb] * DE + k];
        else if (k < DE + DH)  v = *(const float4*)&H[(size_t)sb * DH + (k - DE)];
        else                   v = *(const float4*)&rel_emb[(size_t)q[sb] * DR + (k - DE - DH)];
        *(float4*)&xs[row * XS_P + k] = v;
    }

    // ---- action indices + masks (hoisted) ----
    const int a   = t & 255;
    const int rp  = t >> 8;              // 0..1
    const int rp4 = rp * 4;
    int   ridx[4];
    float msk [4];
    #pragma unroll
    for (int j = 0; j < 4; ++j) {
        ridx[j] = r_space[(size_t)(b0 + rp4 + j) * AA + a];
        msk [j] = r_mask [(size_t)(b0 + rp4 + j) * AA + a];
    }

    cg::this_grid().sync();              // wsb + xs visible everywhere

    // ================= Phase B1: layer 1 (wave owns n-tiles 2w, 2w+1) =======
    {
        f32x4 acc0 = {0.f, 0.f, 0.f, 0.f};
        f32x4 acc1 = {0.f, 0.f, 0.f, 0.f};
        const int nt0 = 2 * w, nt1 = 2 * w + 1;
        #pragma unroll 4
        for (int kt = 0; kt < 16; ++kt) {
            const uint4 af  = build_one(&xs[arow * XS_P + kt * 32 + kb_l], lo);
            const uint4 bv0 = wsb[(size_t)(kt * 16 + nt0) * 64 + l];
            const uint4 bv1 = wsb[(size_t)(kt * 16 + nt1) * 64 + l];
            acc0 = MFMA(asfrag(af), asfrag(bv0), acc0);
            acc1 = MFMA(asfrag(af), asfrag(bv1), acc1);
        }
        #pragma unroll
        for (int v = 0; v < 4; ++v) {    // hi(row r, lane l<32) += lo(row r+8, lane l+32)
            acc0[v] += __shfl_xor(acc0[v], 32, 64);
            acc1[v] += __shfl_xor(acc1[v], 32, 64);
        }
        if (l < 32) {
            const int r4 = (l >> 4) * 4;
            const int n0 = nt0 * 16 + m, n1 = nt1 * 16 + m;
            const float bb0 = b1[n0], bb1 = b1[n1];
            #pragma unroll
            for (int v = 0; v < 4; ++v) {
                hs[(r4 + v) * HS_P + n0] = fmaxf(acc0[v] + bb0, 0.f);
                hs[(r4 + v) * HS_P + n1] = fmaxf(acc1[v] + bb1, 0.f);
            }
        }
    }
    __syncthreads();

    // ================= Phase B2: layer 2 (wave owns n-tile w) ===============
    {
        f32x4 acc = {0.f, 0.f, 0.f, 0.f};
        #pragma unroll 4
        for (int kt = 0; kt < 8; ++kt) {
            const uint4 af = build_one(&hs[arow * HS_P + kt * 32 + kb_l], lo);
            const uint4 bv = wsb[(size_t)(W2B_OFF + (kt * 8 + w) * 64 + l)];
            acc = MFMA(asfrag(af), asfrag(bv), acc);
        }
        #pragma unroll
        for (int v = 0; v < 4; ++v) acc[v] += __shfl_xor(acc[v], 32, 64);
        if (l < 32) {
            const int r4 = (l >> 4) * 4;
            const int n  = w * 16 + m;
            const float bb = b2[n];
            #pragma unroll
            for (int v = 0; v < 4; ++v)
                x2s[(r4 + v) * X2_P + n] = acc[v] + bb;
        }
    }
    __syncthreads();

    // ================= Phase B3: score (wave owns 8 n-tiles) ================
    {
        uint4 sf[4];
        #pragma unroll
        for (int kt = 0; kt < 4; ++kt)
            sf[kt] = build_one(&x2s[arow * X2_P + kt * 32 + kb_l], lo);
        #pragma unroll 2
        for (int i = 0; i < 8; ++i) {
            const int nt = w * 8 + i;
            if (nt >= 63) break;         // wave 7: 7 tiles (uniform branch)
            f32x4 acc = {0.f, 0.f, 0.f, 0.f};
            #pragma unroll
            for (int kt = 0; kt < 4; ++kt) {
                const uint4 bv = wsb[(size_t)(RB_OFF + (nt * 4 + kt) * 64 + l)];
                acc = MFMA(asfrag(sf[kt]), asfrag(bv), acc);
            }
            #pragma unroll
            for (int v = 0; v < 4; ++v) acc[v] += __shfl_xor(acc[v], 32, 64);
            if (l < 32) {
                const int r4 = (l >> 4) * 4;
                const int n  = nt * 16 + m;
                #pragma unroll
                for (int v = 0; v < 4; ++v)
                    scoreL[(r4 + v) * SCL + n] = acc[v];
            }
        }
    }
    __syncthreads();

    // ================= softmax + entropy ====================================
    float lg[4];
    #pragma unroll
    for (int j = 0; j < 4; ++j)
        lg[j] = scoreL[(rp4 + j) * SCL + ridx[j]] - (1.0f - msk[j]) * 1e31f;

    float mx[4];
    #pragma unroll
    for (int j = 0; j < 4; ++j) mx[j] = lg[j];
    #pragma unroll
    for (int off = 32; off >= 1; off >>= 1) {
        #pragma unroll
        for (int j = 0; j < 4; ++j)
            mx[j] = fmaxf(mx[j], __shfl_xor(mx[j], off, 64));
    }
    if (l == 0) {
        #pragma unroll
        for (int j = 0; j < 4; ++j) wredM[w][j] = mx[j];
    }
    __syncthreads();
    {
        const int wb = rp * 4;
        #pragma unroll
        for (int j = 0; j < 4; ++j)
            mx[j] = fmaxf(fmaxf(wredM[wb][j], wredM[wb+1][j]),
                          fmaxf(wredM[wb+2][j], wredM[wb+3][j]));
    }

    float p[4], s[4], sl[4];
    #pragma unroll
    for (int j = 0; j < 4; ++j) {
        const float z = lg[j] - mx[j];
        p[j]  = __expf(z);
        s[j]  = p[j];
        sl[j] = p[j] * z;
    }
    #pragma unroll
    for (int off = 32; off >= 1; off >>= 1) {
        #pragma unroll
        for (int j = 0; j < 4; ++j) {
            s[j]  += __shfl_xor(s[j],  off, 64);
            sl[j] += __shfl_xor(sl[j], off, 64);
        }
    }
    if (l == 0) {
        #pragma unroll
        for (int j = 0; j < 4; ++j) { wredS[w][j] = s[j]; wredL[w][j] = sl[j]; }
    }
    __syncthreads();
    float S[4], SLs[4];
    {
        const int wb = rp * 4;
        #pragma unroll
        for (int j = 0; j < 4; ++j) {
            S  [j] = wredS[wb][j] + wredS[wb+1][j] + wredS[wb+2][j] + wredS[wb+3][j];
            SLs[j] = wredL[wb][j] + wredL[wb+1][j] + wredL[wb+2][j] + wredL[wb+3][j];
        }
    }

    #pragma unroll
    for (int j = 0; j < 4; ++j)
        dist_out[(size_t)(b0 + rp4 + j) * AA + a] = p[j] / S[j];
    if (t == 0) {
        #pragma unroll
        for (int j = 0; j < 4; ++j)
            ent_out[b0 + j] = __logf(S[j]) - SLs[j] / S[j];
    }
    if (t == 256) {
        #pragma unroll
        for (int j = 0; j < 4; ++j)
            ent_out[b0 + 4 + j] = __logf(S[j]) - SLs[j] / S[j];
    }
}

extern "C" void kernel_launch(void* const* d_in, const int* in_sizes, int n_in,
                              void* d_out, int out_size, void* d_ws, size_t ws_size,
                              hipStream_t stream) {
    const int*   e          = (const int*)  d_in[0];
    const int*   q          = (const int*)  d_in[1];
    const float* H          = (const float*)d_in[2];
    const int*   r_space    = (const int*)  d_in[3];
    const float* r_mask     = (const float*)d_in[4];
    const float* entity_emb = (const float*)d_in[5];
    const float* rel_emb    = (const float*)d_in[6];
    const float* W1         = (const float*)d_in[7];
    const float* b1         = (const float*)d_in[8];
    const float* W2         = (const float*)d_in[9];
    const float* b2         = (const float*)d_in[10];

    const int B = in_sizes[0];              // 2048
    float* dist_out = (float*)d_out;                    // [B, 256]
    float* ent_out  = (float*)d_out + (size_t)B * AA;   // [B]
    uint4* wsb      = (uint4*)d_ws;                     // 572 KB packed B-frags

    void* args[] = { (void*)&e, (void*)&q, (void*)&H, (void*)&r_space,
                     (void*)&r_mask, (void*)&entity_emb, (void*)&rel_emb,
                     (void*)&W1, (void*)&b1, (void*)&W2, (void*)&b2,
                     (void*)&wsb, (void*)&dist_out, (void*)&ent_out };
    hipLaunchCooperativeKernel((const void*)policy_kernel,
                               dim3(B / BB), dim3(512), args, 0, stream);
}

// Round 11
// 34.629 us; speedup vs baseline: 1.8791x; 1.8791x over previous
//
#include <hip/hip_runtime.h>

// GraphSearchPolicy, two-kernel MFMA formulation, BB=4, 2 blocks/CU.
// MI355X gfx950. B=2048, A=256, DE=128, DH=256, DR=128, DIN=512, ACT=256, NR=1000.
//
// prep_kernel: packs W1/W2/rel_emb^T into bf16 MFMA B-fragment tiles (d_ws).
// policy_kernel (grid 512 x 512 thr, ~31 KB LDS -> 2 blocks/CU):
//   L1: [4x512]@[512x256] -> h    L2: [4x256]@[256x128] -> x2
//   SC: [4x128]@[128x1008] -> score   then wave-local softmax+entropy.
// A-operand hi/lo split packed into M rows: rows 0-3 = bf16-hi of batch rows,
// rows 4-7 = bf16-residual; one MFMA per (kt,ntile); true row r = C[r]+C[r+4]
// via shfl_xor(.,16) (C mapping HW-verified: col=lane&15, row=(lane>>4)*4+reg).

#define DE   128
#define DH   256
#define DR   128
#define DIN  512
#define ACT  256
#define AA   256
#define BB   4
#define NR   1000
#define SCL  1008            // padded score width (63 n-tiles)

#define XS_P 520             // xs row stride (floats)
#define HS_P 264             // hs row stride
#define X2_P 136             // x2 row stride

#define W2B_OFF 16384        // uint4 offsets into d_ws
#define RB_OFF  20480
#define PREP_T  36608        // 572 tiles * 64 lanes

typedef __attribute__((ext_vector_type(4))) float f32x4;
typedef __attribute__((ext_vector_type(8))) short s16x8;
typedef unsigned int u32;

#define MFMA(a,b,c) __builtin_amdgcn_mfma_f32_16x16x32_bf16(a, b, c, 0, 0, 0)

__device__ __forceinline__ u32 b16(float x) {            // fp32 -> bf16 (RNE)
    u32 u = __float_as_uint(x);
    return (u + 0x7FFFu + ((u >> 16) & 1u)) >> 16;
}
__device__ __forceinline__ float b16f(u32 h) { return __uint_as_float(h << 16); }
__device__ __forceinline__ u32 pack2(float a, float b) { return b16(a) | (b16(b) << 16); }

__device__ __forceinline__ s16x8 asfrag(uint4 v) {
    union { uint4 u; s16x8 s; } c; c.u = v; return c.s;
}

// 8 consecutive fp32 -> ONE bf16 fragment: hi part if !lo, residual if lo.
__device__ __forceinline__ uint4 build_one(const float* p, bool lo) {
    const float4 a = *(const float4*)p;
    const float4 b = *(const float4*)(p + 4);
    const float f[8] = {a.x, a.y, a.z, a.w, b.x, b.y, b.z, b.w};
    u32 o[8];
    #pragma unroll
    for (int i = 0; i < 8; ++i) {
        const u32  h = b16(f[i]);
        const float r = f[i] - b16f(h);
        o[i] = lo ? b16(r) : h;
    }
    uint4 v;
    v.x = o[0] | (o[1] << 16); v.y = o[2] | (o[3] << 16);
    v.z = o[4] | (o[5] << 16); v.w = o[6] | (o[7] << 16);
    return v;
}

// ---------------------------------------------------------------- prep
// B-fragment tiles: value reg v of lane l in tile (kt,nt) covers
// n = nt*16 + (l&15), k = kt*32 + (l>>4)*8 + {2v, 2v+1}.
__global__ __launch_bounds__(256) void prep_kernel(
    const float* __restrict__ W1, const float* __restrict__ W2,
    const float* __restrict__ rel_emb, uint4* __restrict__ wsb)
{
    const int id = blockIdx.x * 256 + threadIdx.x;       // 0..36607
    const int l  = id & 63;
    const int tl = id >> 6;                              // tile 0..571
    const int kb_l = (l >> 4) * 8;
    const int n_l  = l & 15;
    float f[8];
    if (tl < 256) {                                      // W1B: tl = kt*16+nt
        const int kt = tl >> 4, nt = tl & 15;
        const int kb = kt * 32 + kb_l, n = nt * 16 + n_l;
        #pragma unroll
        for (int i = 0; i < 8; ++i) f[i] = W1[(size_t)(kb + i) * ACT + n];
    } else if (tl < 320) {                               // W2B: tl-256 = kt*8+nt
        const int t2 = tl - 256;
        const int kt = t2 >> 3, nt = t2 & 7;
        const int kb = kt * 32 + kb_l, n = nt * 16 + n_l;
        #pragma unroll
        for (int i = 0; i < 8; ++i) f[i] = W2[(size_t)(kb + i) * DR + n];
    } else {                                             // RB: tl-320 = nt*4+kt
        const int t3 = tl - 320;                         // 0..251
        const int nt = t3 >> 2, kt = t3 & 3;
        const int kb = kt * 32 + kb_l, n = nt * 16 + n_l;
        #pragma unroll
        for (int i = 0; i < 8; ++i)
            f[i] = (n < NR) ? rel_emb[(size_t)n * DR + kb + i] : 0.f;
    }
    uint4 o;
    o.x = pack2(f[0], f[1]); o.y = pack2(f[2], f[3]);
    o.z = pack2(f[4], f[5]); o.w = pack2(f[6], f[7]);
    wsb[id] = o;
}

// ---------------------------------------------------------------- main
__global__ __launch_bounds__(512, 2) void policy_kernel(
    const int*   __restrict__ e,
    const int*   __restrict__ q,
    const float* __restrict__ H,
    const int*   __restrict__ r_space,
    const float* __restrict__ r_mask,
    const float* __restrict__ entity_emb,
    const float* __restrict__ rel_emb,
    const float* __restrict__ b1,
    const float* __restrict__ b2,
    const uint4* __restrict__ wsb,
    float* __restrict__ dist_out,
    float* __restrict__ ent_out)
{
    const int t  = threadIdx.x;          // 0..511
    const int b0 = blockIdx.x * BB;
    const int l  = t & 63;
    const int w  = t >> 6;               // wave 0..7
    const int m  = l & 15;               // fragment row slot
    const bool mval = (m < 8);           // rows 0-3 hi, 4-7 lo, 8-15 zero
    const int  arow = m & 3;
    const bool lo   = (m & 4) != 0;
    const int kb_l  = (l >> 4) * 8;

    __shared__ __align__(16) float xs[BB * XS_P];    //  8.3 KB
    __shared__ __align__(16) float hs[BB * HS_P];    //  4.2 KB
    __shared__ __align__(16) float x2s[BB * X2_P];   //  2.2 KB
    __shared__ float scoreL[BB * SCL];               // 16.1 KB

    // ---- early loads: wave w<4 owns batch row w; 4 actions/lane ----
    int   ridx[4];
    float msk [4];
    if (w < 4) {
        #pragma unroll
        for (int c = 0; c < 4; ++c) {
            ridx[c] = r_space[(size_t)(b0 + w) * AA + l + 64 * c];
            msk [c] = r_mask [(size_t)(b0 + w) * AA + l + 64 * c];
        }
    }

    // ---- stage X = concat(E,H,Q): 1 float4/thread ----
    {
        const int row = t >> 7;          // 0..3
        const int k   = (t & 127) * 4;   // 0..508
        const int sb  = b0 + row;
        float4 v;
        if (k < DE)            v = *(const float4*)&entity_emb[(size_t)e[sb] * DE + k];
        else if (k < DE + DH)  v = *(const float4*)&H[(size_t)sb * DH + (k - DE)];
        else                   v = *(const float4*)&rel_emb[(size_t)q[sb] * DR + (k - DE - DH)];
        *(float4*)&xs[row * XS_P + k] = v;
    }
    __syncthreads();

    // ================= layer 1: wave owns n-tiles {2w, 2w+1} ================
    {
        f32x4 acc0 = {0.f, 0.f, 0.f, 0.f};
        f32x4 acc1 = {0.f, 0.f, 0.f, 0.f};
        const int nt0 = 2 * w, nt1 = 2 * w + 1;
        #pragma unroll 4
        for (int kt = 0; kt < 16; ++kt) {
            uint4 af = {0, 0, 0, 0};
            if (mval) af = build_one(&xs[arow * XS_P + kt * 32 + kb_l], lo);
            const uint4 bv0 = wsb[(size_t)(kt * 16 + nt0) * 64 + l];
            const uint4 bv1 = wsb[(size_t)(kt * 16 + nt1) * 64 + l];
            acc0 = MFMA(asfrag(af), asfrag(bv0), acc0);
            acc1 = MFMA(asfrag(af), asfrag(bv1), acc1);
        }
        #pragma unroll
        for (int v = 0; v < 4; ++v) {    // row r (lanes 0-15) += row r+4 (lanes 16-31)
            acc0[v] += __shfl_xor(acc0[v], 16, 64);
            acc1[v] += __shfl_xor(acc1[v], 16, 64);
        }
        if (l < 16) {                    // C: lanes 0-15 hold rows v=0..3, col=l
            const int n0 = nt0 * 16 + l, n1 = nt1 * 16 + l;
            const float bb0 = b1[n0], bb1 = b1[n1];
            #pragma unroll
            for (int v = 0; v < 4; ++v) {
                hs[v * HS_P + n0] = fmaxf(acc0[v] + bb0, 0.f);
                hs[v * HS_P + n1] = fmaxf(acc1[v] + bb1, 0.f);
            }
        }
    }
    __syncthreads();

    // ================= layer 2: wave owns n-tile w ==========================
    {
        f32x4 acc = {0.f, 0.f, 0.f, 0.f};
        #pragma unroll 4
        for (int kt = 0; kt < 8; ++kt) {
            uint4 af = {0, 0, 0, 0};
            if (mval) af = build_one(&hs[arow * HS_P + kt * 32 + kb_l], lo);
            const uint4 bv = wsb[(size_t)(W2B_OFF + (kt * 8 + w) * 64 + l)];
            acc = MFMA(asfrag(af), asfrag(bv), acc);
        }
        #pragma unroll
        for (int v = 0; v < 4; ++v) acc[v] += __shfl_xor(acc[v], 16, 64);
        if (l < 16) {
            const int n = w * 16 + l;
            const float bb = b2[n];
            #pragma unroll
            for (int v = 0; v < 4; ++v)
                x2s[v * X2_P + n] = acc[v] + bb;
        }
    }
    __syncthreads();

    // ================= score: wave owns 8 n-tiles ===========================
    {
        uint4 sf[4] = {{0,0,0,0}, {0,0,0,0}, {0,0,0,0}, {0,0,0,0}};
        #pragma unroll
        for (int kt = 0; kt < 4; ++kt)
            if (mval) sf[kt] = build_one(&x2s[arow * X2_P + kt * 32 + kb_l], lo);
        #pragma unroll 2
        for (int i = 0; i < 8; ++i) {
            const int nt = w * 8 + i;
            if (nt >= 63) break;         // wave 7: 7 tiles (uniform branch)
            f32x4 acc = {0.f, 0.f, 0.f, 0.f};
            #pragma unroll
            for (int kt = 0; kt < 4; ++kt) {
                const uint4 bv = wsb[(size_t)(RB_OFF + (nt * 4 + kt) * 64 + l)];
                acc = MFMA(asfrag(sf[kt]), asfrag(bv), acc);
            }
            #pragma unroll
            for (int v = 0; v < 4; ++v) acc[v] += __shfl_xor(acc[v], 16, 64);
            if (l < 16) {
                const int n = nt * 16 + l;
                #pragma unroll
                for (int v = 0; v < 4; ++v)
                    scoreL[v * SCL + n] = acc[v];
            }
        }
    }
    __syncthreads();

    // ================= wave-local softmax + entropy (waves 0-3) =============
    if (w < 4) {
        float lg[4];
        #pragma unroll
        for (int c = 0; c < 4; ++c)
            lg[c] = scoreL[w * SCL + ridx[c]] - (1.0f - msk[c]) * 1e31f;

        float mx = fmaxf(fmaxf(lg[0], lg[1]), fmaxf(lg[2], lg[3]));
        #pragma unroll
        for (int off = 32; off >= 1; off >>= 1)
            mx = fmaxf(mx, __shfl_xor(mx, off, 64));

        float p[4], S = 0.f, SL = 0.f;
        #pragma unroll
        for (int c = 0; c < 4; ++c) {
            const float z = lg[c] - mx;
            p[c] = __expf(z);
            S  += p[c];
            SL += p[c] * z;
        }
        #pragma unroll
        for (int off = 32; off >= 1; off >>= 1) {
            S  += __shfl_xor(S,  off, 64);
            SL += __shfl_xor(SL, off, 64);
        }

        const float inv = 1.0f / S;
        #pragma unroll
        for (int c = 0; c < 4; ++c)
            dist_out[(size_t)(b0 + w) * AA + l + 64 * c] = p[c] * inv;
        if (l == 0)
            ent_out[b0 + w] = __logf(S) - SL * inv;
    }
}

extern "C" void kernel_launch(void* const* d_in, const int* in_sizes, int n_in,
                              void* d_out, int out_size, void* d_ws, size_t ws_size,
                              hipStream_t stream) {
    const int*   e          = (const int*)  d_in[0];
    const int*   q          = (const int*)  d_in[1];
    const float* H          = (const float*)d_in[2];
    const int*   r_space    = (const int*)  d_in[3];
    const float* r_mask     = (const float*)d_in[4];
    const float* entity_emb = (const float*)d_in[5];
    const float* rel_emb    = (const float*)d_in[6];
    const float* W1         = (const float*)d_in[7];
    const float* b1         = (const float*)d_in[8];
    const float* W2         = (const float*)d_in[9];
    const float* b2         = (const float*)d_in[10];

    const int B = in_sizes[0];              // 2048
    float* dist_out = (float*)d_out;                    // [B, 256]
    float* ent_out  = (float*)d_out + (size_t)B * AA;   // [B]
    uint4* wsb      = (uint4*)d_ws;                     // 572 KB packed B-frags

    prep_kernel<<<PREP_T / 256, 256, 0, stream>>>(W1, W2, rel_emb, wsb);
    policy_kernel<<<B / BB, 512, 0, stream>>>(
        e, q, H, r_space, r_mask, entity_emb, rel_emb,
        b1, b2, wsb, dist_out, ent_out);
}